// Round 6
// baseline (440.859 us; speedup 1.0000x reference)
//
#include <hip/hip_runtime.h>

// Problem constants (from reference):
//   N = 512, DX = 1/511, DT = 1e-7, NUM_STEPS = 200 -> 199 output states
//   MB = 256 (material boundary column), interface column ii = 255
#define GN 512
#define GNN (GN * GN)
#define NSTEPS 199

// Persistent async temporal fusion:
//   TS = 16 output tile, KS = 8 fused steps per K-block, HS = 32 held tile.
//   ONE WAVE per tile (lane grid 8x8, 4x4 patch/lane, all in registers).
//   ONE kernel launch (cooperative, co-residency guaranteed). Between
//   K-blocks, tiles sync ONLY with their 8 neighbors via per-tile flags:
//     producer: final-slice owned 16x16 via agent-scope stores (write-through
//               to the coherent point), s_waitcnt vmcnt(0), relaxed agent
//               flag store (single writer -> no release fence, no wbl2).
//     consumer: spin on 8 neighbor flags with relaxed agent loads (no
//               buffer_inv), then reload held tile with agent loads.
//   No grid barrier, no per-dispatch L2 flush/invalidate, no launch gaps.
//   Slices have unique addresses (out + s*GNN) -> reads can never observe
//   "too new" data; flag only gates "not yet written".
#define TS 16
#define KS 8
#define NKB ((NSTEPS + KS - 1) / KS)   // 25 (last K-block runs 7 steps)
#define PR 4
#define PC 4

// Precomputed coefficients (double -> float once):
__constant__ const float kCdiff = (float)(1e-7 * 511.0 * 511.0); // DT/DX^2
__constant__ const float kCadv  = (float)(1e-7 * 511.0 / 2.0);   // DT/(2DX)
__constant__ const float kCrea  = 1e-7f;                          // DT

// DPP lane+-1 exchange (verified passing in the 371us round):
#define DPP_SHR1(x) __int_as_float(__builtin_amdgcn_mov_dpp( \
    __float_as_int(x), 0x138, 0xf, 0xf, true))
#define DPP_SHL1(x) __int_as_float(__builtin_amdgcn_mov_dpp( \
    __float_as_int(x), 0x130, 0xf, 0xf, true))
#define BPERM(a, x) __int_as_float(__builtin_amdgcn_ds_bpermute( \
    (a), __float_as_int(x)))

// Agent-scope (cross-XCD coherent) 4B load/store. Relaxed ordering: no
// cache-maintenance instructions; coherence comes from sc-bit write-through/
// bypass lowering for __HIP_MEMORY_SCOPE_AGENT on gfx950.
__device__ __forceinline__ float agent_load_f(const float* p) {
    unsigned u = __hip_atomic_load((const unsigned*)p, __ATOMIC_RELAXED,
                                   __HIP_MEMORY_SCOPE_AGENT);
    return __uint_as_float(u);
}
__device__ __forceinline__ void agent_store_f(float* p, float v) {
    __hip_atomic_store((unsigned*)p, __float_as_uint(v), __ATOMIC_RELAXED,
                       __HIP_MEMORY_SCOPE_AGENT);
}

// One fused step SRC->DST (identical math/structure to the verified 371us
// kernel). SIDX is the ABSOLUTE step index; FINAL selects agent-scope
// publishing for the K-block's last slice (read by neighbor tiles).
#define DO_STEP(SRC, DST, TMI, TPI, TMO, TPO, SIDX, FINAL)                    \
{                                                                             \
    float tlE[PR], trE[PR];                                                   \
    _Pragma("unroll") for (int r = 0; r < PR; ++r) {                          \
        tlE[r] = DPP_SHR1(SRC[r][PC - 1]);                                    \
        trE[r] = DPP_SHL1(SRC[r][0]);                                         \
    }                                                                         \
    _Pragma("unroll") for (int ri = 0; ri < PR; ++ri) {                       \
        const int r = (ri == 0) ? 1 : (ri == 1) ? 2 : (ri == 2) ? 0 : 3;      \
        _Pragma("unroll") for (int c = 0; c < PC; ++c) {                      \
            const float tc = SRC[r][c];                                       \
            const float tm = (r > 0)      ? SRC[r - 1][c] : TMI[c];           \
            const float tp = (r < PR - 1) ? SRC[r + 1][c] : TPI[c];           \
            const float tl = (c > 0)      ? SRC[r][c - 1] : tlE[r];           \
            const float tr = (c < PC - 1) ? SRC[r][c + 1] : trE[r];           \
            const float t2 = tc * tc;                                         \
            const float dv = tp - tm;                                         \
            const float dh = tr - tl;                                         \
            const float lap = __builtin_fmaf(-4.0f, tc, (tm + tp) + (tl + tr)); \
            const float advt = __builtin_fmaf(t2, dv, -(tc * dh));            \
            const float reat = __builtin_fmaf(t2, tc - 1.0f, tc);             \
            float v = __builtin_fmaf(nckA[c], advt, tc);                      \
            v = __builtin_fmaf(ckD[c], lap, v);                               \
            v = __builtin_fmaf(ckR[c], reat, v);                              \
            if (hasIface) {                                                   \
                const float vif = __builtin_fmaf(k1, tr, k2 * tl) * inv12;    \
                v = (pc0 + c == 255) ? vif : v;                               \
            }                                                                 \
            DST[r][c] = v;                                                    \
        }                                                                     \
    }                                                                         \
    /* boundary fixes (rows before cols, matching reference order) */         \
    if (fTop && rg == 2) { _Pragma("unroll")                                  \
        for (int c = 0; c < PC; ++c) DST[0][c] = DST[1][c]; }                 \
    if (fBot && rg == 5) { _Pragma("unroll")                                  \
        for (int c = 0; c < PC; ++c) DST[PR - 1][c] = DST[PR - 2][c]; }       \
    if (fL && cg == 2) { _Pragma("unroll")                                    \
        for (int r = 0; r < PR; ++r) DST[r][0] = DST[r][1]; }                 \
    if (fR && cg == 5) { _Pragma("unroll")                                    \
        for (int r = 0; r < PR; ++r) DST[r][PC - 1] = DST[r][PC - 2]; }       \
    /* issue next step's vertical exchange early (post-fix values) */         \
    _Pragma("unroll") for (int c = 0; c < PC; ++c) {                          \
        TMO[c] = BPERM(aU, DST[PR - 1][c]);                                   \
        TPO[c] = BPERM(aD, DST[0][c]);                                        \
    }                                                                         \
    if (storeLane) {                                                          \
        float* __restrict__ dsts = out + (size_t)(SIDX) * GNN + lofs;         \
        if (FINAL) {                                                          \
            _Pragma("unroll") for (int r = 0; r < PR; ++r)                    \
                _Pragma("unroll") for (int c = 0; c < PC; ++c)                \
                    agent_store_f(dsts + r * GN + c, DST[r][c]);              \
        } else {                                                              \
            _Pragma("unroll") for (int r = 0; r < PR; ++r) {                  \
                float4 v4;                                                    \
                v4.x = DST[r][0]; v4.y = DST[r][1];                           \
                v4.z = DST[r][2]; v4.w = DST[r][3];                           \
                *reinterpret_cast<float4*>(dsts + r * GN) = v4;               \
            }                                                                 \
        }                                                                     \
    }                                                                         \
}

__global__ __launch_bounds__(64) void adr_persist(
    const float* __restrict__ u0, float* __restrict__ out,
    const float* __restrict__ pk1, const float* __restrict__ pk2,
    const float* __restrict__ pa1, const float* __restrict__ pa2,
    unsigned* __restrict__ flags)
{
    const int lane = threadIdx.x & 63;
    const int cg = lane & 7;        // col group
    const int rg = lane >> 3;       // row group
    const int bx = blockIdx.x & 31; // tile col
    const int by = blockIdx.x >> 5; // tile row
    const int tileId = blockIdx.x;
    const int rb = by * TS - KS;    // held-region base row (may be <0)
    const int cb = bx * TS - KS;    // held-region base col
    const int pr0 = rb + rg * PR;   // lane's first global row
    const int pc0 = cb + cg * PC;   // lane's first global col
    const int lofs = pr0 * GN + pc0;

    const float k1 = pk1[0];
    const float k2 = pk2[0];
    const float a1 = pa1[0];
    const float a2 = pa2[0];
    const float inv12 = 1.0f / (k1 + k2);

    // Per-lane per-patch-column material constants.
    float nckA[PC], ckD[PC], ckR[PC];
    #pragma unroll
    for (int c = 0; c < PC; ++c) {
        const int gc = pc0 + c;
        const float kap = (gc < 256) ? k1 : k2;
        const float alp = (gc < 256) ? a1 : a2;
        nckA[c] = -(kap * kCadv);
        ckD[c]  = alp * kCdiff;
        ckR[c]  = kCrea * kap;
    }

    // Vertical bpermute byte addresses.
    const int aU = ((lane + 56) & 63) << 2;
    const int aD = ((lane + 8) & 63) << 2;

    // Wave-uniform roles.
    const bool interior = (bx > 0 && bx < 31 && by > 0 && by < 31);
    const bool hasIface = (bx == 15 || bx == 16);
    const bool fTop = (by == 0), fBot = (by == 31);
    const bool fL = (bx == 0), fR = (bx == 31);
    const bool storeLane = (rg >= 2 && rg <= 5 && cg >= 2 && cg <= 5);

    // Clamped per-patch global offsets (loop-invariant across K-blocks).
    int rowoff[PR], coloff[PC];
    #pragma unroll
    for (int r = 0; r < PR; ++r)
        rowoff[r] = min(max(pr0 + r, 0), GN - 1) * GN;
    #pragma unroll
    for (int c = 0; c < PC; ++c)
        coloff[c] = min(max(pc0 + c, 0), GN - 1);

    // Neighbor flag id for lanes 0..7 (8 surrounding tiles, clamped; clamp
    // to self is harmless — own flag is always >= kb when polled).
    int nbid = 0;
    {
        const int q = lane + (lane >= 4 ? 1 : 0);   // 0..8 skipping center
        const int nbx = min(max(bx + (q % 3) - 1, 0), 31);
        const int nby = min(max(by + (q / 3) - 1, 0), 31);
        nbid = nby * 32 + nbx;
    }

    float A[PR][PC], B[PR][PC];
    float tm0[PC], tp0[PC], tm1[PC], tp1[PC];

    #pragma unroll 1
    for (int kb = 0; kb < NKB; ++kb) {
        const int ns = (NSTEPS - kb * KS < KS) ? (NSTEPS - kb * KS) : KS;

        if (kb == 0) {
            // Initial load from u0 (normal loads; visible via launch acquire).
            if (interior) {
                #pragma unroll
                for (int r = 0; r < PR; ++r) {
                    const float4 v = *reinterpret_cast<const float4*>(
                        u0 + (pr0 + r) * GN + pc0);
                    A[r][0] = v.x; A[r][1] = v.y;
                    A[r][2] = v.z; A[r][3] = v.w;
                }
            } else {
                #pragma unroll
                for (int r = 0; r < PR; ++r)
                    #pragma unroll
                    for (int c = 0; c < PC; ++c)
                        A[r][c] = u0[rowoff[r] + coloff[c]];
            }
        } else {
            // Wait for the 8 neighbors to have completed K-block kb-1.
            bool ready = false;
            while (!ready) {
                unsigned v = 0xFFFFFFFFu;
                if (lane < 8)
                    v = __hip_atomic_load(&flags[nbid], __ATOMIC_RELAXED,
                                          __HIP_MEMORY_SCOPE_AGENT);
                ready = __all((lane >= 8) || (v >= (unsigned)kb));
                if (!ready) __builtin_amdgcn_s_sleep(4);
            }
            asm volatile("" ::: "memory");
            // Reload held tile from the previous K-block's final slice
            // (written ONLY via agent stores -> coherent point has it).
            const float* sl = out + (size_t)(kb * KS - 1) * GNN;
            #pragma unroll
            for (int r = 0; r < PR; ++r)
                #pragma unroll
                for (int c = 0; c < PC; ++c)
                    A[r][c] = agent_load_f(sl + rowoff[r] + coloff[c]);
        }

        // Pre-issue this K-block's first vertical exchange.
        #pragma unroll
        for (int c = 0; c < PC; ++c) {
            tm0[c] = BPERM(aU, A[PR - 1][c]);
            tp0[c] = BPERM(aD, A[0][c]);
        }

        // Ping-pong step loop (uniform breaks; ns <= KS).
        const int base = kb * KS;
        #pragma unroll
        for (int s = 0; s < KS; s += 2) {
            if (s >= ns) break;
            DO_STEP(A, B, tm0, tp0, tm1, tp1, base + s, (s == ns - 1))
            if (s + 1 >= ns) break;
            DO_STEP(B, A, tm1, tp1, tm0, tp0, base + s + 1, (s + 1 == ns - 1))
        }

        // Publish completion: drain all stores, then relaxed agent flag
        // store (single writer; data went write-through, so no release
        // fence / L2 writeback needed).
        asm volatile("s_waitcnt vmcnt(0)" ::: "memory");
        if (lane == 0)
            __hip_atomic_store(&flags[tileId], (unsigned)(kb + 1),
                               __ATOMIC_RELAXED, __HIP_MEMORY_SCOPE_AGENT);
    }
}

extern "C" void kernel_launch(void* const* d_in, const int* in_sizes, int n_in,
                              void* d_out, int out_size, void* d_ws, size_t ws_size,
                              hipStream_t stream) {
    (void)in_sizes; (void)n_in; (void)out_size; (void)ws_size;

    const float* u0 = (const float*)d_in[0];
    const float* k1 = (const float*)d_in[1];
    const float* k2 = (const float*)d_in[2];
    const float* a1 = (const float*)d_in[3];
    const float* a2 = (const float*)d_in[4];
    float* out = (float*)d_out;
    unsigned* flags = (unsigned*)d_ws;

    const int ntiles = (GN / TS) * (GN / TS);   // 1024 tiles = 1024 waves

    // Re-zero flags every graph replay (captured on the stream).
    hipMemsetAsync(flags, 0, ntiles * sizeof(unsigned), stream);

    void* args[] = {(void*)&u0, (void*)&out, (void*)&k1, (void*)&k2,
                    (void*)&a1, (void*)&a2, (void*)&flags};
    hipLaunchCooperativeKernel((void*)adr_persist, dim3(ntiles), dim3(64),
                               args, 0, stream);
}